// Round 5
// baseline (140.955 us; speedup 1.0000x reference)
//
#include <hip/hip_runtime.h>

// AffineGPT2Attention: B=4, S=1024, D=1024, H=16, Dh=64
// Pipeline: cast hs->bf16; transpose+cast weights; QKV GEMM (bf16 MFMA, scatter
// epilogue to Q[b][h][s][d] (pre-scaled by 0.125*log2e), K[b][h][s][d],
// Vt[b][h][d][s]); flash attention (1-wave blocks, 16q/wave, direct-global
// K/V frags); proj GEMM with bias+affine -> f32 out.

typedef __attribute__((ext_vector_type(4))) float  fx4;
typedef __attribute__((ext_vector_type(4))) short  sx4;
typedef __attribute__((ext_vector_type(8))) short  sx8;
typedef __attribute__((ext_vector_type(4))) float  f32x4;
typedef __attribute__((ext_vector_type(8))) __bf16 bf16x8;

#define DEVI static __device__ __forceinline__

DEVI short f2bf(float f) {  // f32 -> bf16 (RNE)
  unsigned u = __builtin_bit_cast(unsigned, f);
  u = (u + 0x7FFFu + ((u >> 16) & 1u)) >> 16;
  return (short)u;
}

DEVI fx4 mfma16(sx8 a, sx8 b, fx4 c) {
  return __builtin_amdgcn_mfma_f32_16x16x32_bf16(
      __builtin_bit_cast(bf16x8, a), __builtin_bit_cast(bf16x8, b), c, 0, 0, 0);
}

DEVI void gl_lds16(const void* g, void* l) {  // async global->LDS, 16B/lane
  __builtin_amdgcn_global_load_lds(
      (const __attribute__((address_space(1))) void*)g,
      (__attribute__((address_space(3))) void*)l, 16, 0, 0);
}

// ---------------- elementwise f32 -> bf16 cast (vectorized) ----------------
__global__ __launch_bounds__(256) void cast_bf16(const float* __restrict__ in,
                                                 short* __restrict__ out, int n4) {
  int i = blockIdx.x * blockDim.x + threadIdx.x;
  if (i < n4) {
    f32x4 v = *(const f32x4*)&in[(size_t)i * 4];
    sx4 o;
#pragma unroll
    for (int j = 0; j < 4; ++j) o[j] = f2bf(v[j]);
    *(sx4*)&out[(size_t)i * 4] = o;
  }
}

// ---------------- transpose + cast: in[R][C] f32 -> out[C][R] bf16 ----------
__global__ __launch_bounds__(256) void transpose_bf16(const float* __restrict__ in,
                                                      short* __restrict__ out,
                                                      int R, int C) {
  __shared__ float t[32][33];
  int tx = threadIdx.x & 31, ty = threadIdx.x >> 5;
  int r0 = blockIdx.y * 32, c0 = blockIdx.x * 32;
#pragma unroll
  for (int i = 0; i < 4; ++i)
    t[ty + i * 8][tx] = in[(size_t)(r0 + ty + i * 8) * C + c0 + tx];
  __syncthreads();
#pragma unroll
  for (int i = 0; i < 4; ++i)
    out[(size_t)(c0 + ty + i * 8) * R + r0 + tx] = f2bf(t[tx][ty + i * 8]);
}

// ---------------- GEMM: C[M][N] = A[M][K] @ Bt[N][K]^T ----------------------
// BM=BN=128, BK=64, 4 waves (2x2), each wave 64x64 = 4x4 frags of 16x16x32.
// EPI 0: qkv scatter epilogue (+bias, Q pre-scaled). EPI 1: proj (+bias,affine).
template <int EPI>
__global__ __launch_bounds__(256) void gemm_bt(
    const short* __restrict__ A, const short* __restrict__ Bt,
    const float* __restrict__ bias, const float* __restrict__ aw,
    const float* __restrict__ ab, short* __restrict__ Qg, short* __restrict__ Kg,
    short* __restrict__ Vtg, float* __restrict__ Out, int M, int N, int K) {
  __shared__ __align__(16) short As[128][64];
  __shared__ __align__(16) short Bs[128][64];
  const int tid = threadIdx.x, lane = tid & 63, w = tid >> 6;
  const int bn = blockIdx.x, bm = blockIdx.y;
  const int wm = w >> 1, wn = w & 1;
  const int c0 = lane & 15, g = lane >> 4;
  const int lr8 = lane >> 3;              // row within 8-row staging chunk
  const int ls8 = (lane & 7) ^ lr8;       // inverse-swizzled source slot
  fx4 acc[4][4] = {};

  for (int kt = 0; kt < K; kt += 64) {
#pragma unroll
    for (int i = 0; i < 4; ++i) {
      int r = w * 32 + i * 8;
      gl_lds16(&A[(size_t)(bm * 128 + r + lr8) * K + kt + ls8 * 8], &As[r][0]);
      gl_lds16(&Bt[(size_t)(bn * 128 + r + lr8) * K + kt + ls8 * 8], &Bs[r][0]);
    }
    __syncthreads();
#pragma unroll
    for (int kk = 0; kk < 2; ++kk) {
      sx8 af[4], bf[4];
      int sb = kk * 4 + g;
#pragma unroll
      for (int m = 0; m < 4; ++m) {
        int row = wm * 64 + m * 16 + c0;
        af[m] = *(const sx8*)&As[row][(sb ^ (row & 7)) * 8];
      }
#pragma unroll
      for (int n = 0; n < 4; ++n) {
        int row = wn * 64 + n * 16 + c0;
        bf[n] = *(const sx8*)&Bs[row][(sb ^ (row & 7)) * 8];
      }
#pragma unroll
      for (int m = 0; m < 4; ++m)
#pragma unroll
        for (int n = 0; n < 4; ++n) acc[m][n] = mfma16(af[m], bf[n], acc[m][n]);
    }
    __syncthreads();
  }

  // epilogue: C/D layout: row = (lane>>4)*4 + r, col = lane&15 (within frag)
  const float SCALE_Q = 0.125f * 1.4426950408889634f;  // fold 1/sqrt(64)*log2e
#pragma unroll
  for (int m = 0; m < 4; ++m) {
#pragma unroll
    for (int n = 0; n < 4; ++n) {
      int col = bn * 128 + wn * 64 + n * 16 + c0;
      int row0 = bm * 128 + wm * 64 + m * 16 + g * 4;
      if (EPI == 0) {
        float bv = bias[col];
        int b = row0 >> 10, s0 = row0 & 1023;
        if (col < 1024) {
          int h = col >> 6, d = col & 63;
          size_t base = ((size_t)(b * 16 + h) * 1024) * 64 + d;
#pragma unroll
          for (int r = 0; r < 4; ++r)
            Qg[base + (size_t)(s0 + r) * 64] = f2bf((acc[m][n][r] + bv) * SCALE_Q);
        } else if (col < 2048) {
          int c = col - 1024, h = c >> 6, d = c & 63;
          size_t base = ((size_t)(b * 16 + h) * 1024) * 64 + d;
#pragma unroll
          for (int r = 0; r < 4; ++r)
            Kg[base + (size_t)(s0 + r) * 64] = f2bf(acc[m][n][r] + bv);
        } else {
          int c = col - 2048, h = c >> 6, d = c & 63;
          sx4 v;
#pragma unroll
          for (int r = 0; r < 4; ++r) v[r] = f2bf(acc[m][n][r] + bv);
          *(sx4*)&Vtg[((size_t)(b * 16 + h) * 64 + d) * 1024 + s0] = v;
        }
      } else {
        float bv = bias[col], wv = aw[col], av = ab[col];
#pragma unroll
        for (int r = 0; r < 4; ++r)
          Out[(size_t)(row0 + r) * N + col] = (acc[m][n][r] + bv) * wv + av;
      }
    }
  }
}

// ---------------- flash attention (causal), 1-wave blocks -------------------
// Grid 4096: bid -> j = 63 - (bid>>6) (16-row q-slice, long waves first),
// bh = bid & 63. Each block = ONE wave, 16 q rows, KVBLK=64.
// K/V frags direct from global (L2-resident); P through 2KB LDS.
// Scores pre-scaled (Q folded with 0.125*log2e) -> p = exp2(z - m).
// S^T = K @ Q^T  (C/D: row=kv, col=q -> q lane-local => cheap softmax)
// O^T = Vt @ P^T (C/D: row=d,  col=q)
// NOTE: the LAST kv-tile always needs the causal mask (kv_max > q_min for
// every slice length), so domask = (kvt == ntiles-1) — predicate on kv0 vs
// q0+15 was WRONG for j%4==3 (round-4 bug).
__global__ __launch_bounds__(64, 4) void attn_kernel(const short* __restrict__ Qg,
                                                     const short* __restrict__ Kg,
                                                     const short* __restrict__ Vtg,
                                                     short* __restrict__ AO) {
  __shared__ __align__(16) short Ps[16 * 64];  // 2 KB
  const int lane = threadIdx.x & 63;
  const int bid = blockIdx.x;
  const int j = 63 - (bid >> 6), bh = bid & 63;
  const int b = bh >> 4, h = bh & 15;
  const int c0 = lane & 15, g = lane >> 4;
  const int q0 = j << 4;
  const short* Qp = Qg + (size_t)bh * 65536;
  const short* Kp = Kg + (size_t)bh * 65536;
  const short* Vp = Vtg + (size_t)bh * 65536;
  const int s8 = (c0 & 7) * 8;  // P swizzle

  sx8 qf[2];  // B-frags of Q: col=q (lane&15), k=d ((lane>>4)*8+jj)
#pragma unroll
  for (int kk = 0; kk < 2; ++kk)
    qf[kk] = *(const sx8*)&Qp[(size_t)(q0 + c0) * 64 + kk * 32 + g * 8];

  fx4 o[4] = {};
  fx4 st[4];
  float mrun = -1e30f, lrun = 0.f;
  const int ntiles = (q0 + 79) >> 6;  // causal: kv <= q0+15
  const int q_glob = q0 + c0;

  for (int kvt = 0; kvt < ntiles; ++kvt) {
    const int kv0 = kvt * 64;

    // S^T = K @ Q^T : 4 kv-frags, K frags direct from global
    __builtin_amdgcn_s_setprio(1);
#pragma unroll
    for (int mf = 0; mf < 4; ++mf) {
      const short* kr = &Kp[(size_t)(kv0 + mf * 16 + c0) * 64 + g * 8];
      sx8 kf0 = *(const sx8*)kr;
      sx8 kf1 = *(const sx8*)(kr + 32);
      fx4 z = {0.f, 0.f, 0.f, 0.f};
      z = mfma16(kf0, qf[0], z);
      st[mf] = mfma16(kf1, qf[1], z);
    }
    __builtin_amdgcn_s_setprio(0);

    // online softmax (fixed q per lane)
    float pmax = -1e30f;
    if (kvt == ntiles - 1) {  // diagonal tile: apply causal mask
#pragma unroll
      for (int mf = 0; mf < 4; ++mf)
#pragma unroll
        for (int r = 0; r < 4; ++r) {
          int kv = kv0 + mf * 16 + g * 4 + r;
          float z = (kv > q_glob) ? -1e30f : st[mf][r];
          st[mf][r] = z;
          pmax = fmaxf(pmax, z);
        }
    } else {
#pragma unroll
      for (int mf = 0; mf < 4; ++mf)
#pragma unroll
        for (int r = 0; r < 4; ++r) pmax = fmaxf(pmax, st[mf][r]);
    }
    pmax = fmaxf(pmax, __shfl_xor(pmax, 16));
    pmax = fmaxf(pmax, __shfl_xor(pmax, 32));
    float mnew = fmaxf(mrun, pmax);
    float alpha = __builtin_amdgcn_exp2f(mrun - mnew);
    float psum = 0.f;
#pragma unroll
    for (int mf = 0; mf < 4; ++mf) {
      sx4 pv;
#pragma unroll
      for (int r = 0; r < 4; ++r) {
        float pp = __builtin_amdgcn_exp2f(st[mf][r] - mnew);
        psum += pp;
        pv[r] = f2bf(pp);
      }
      *(sx4*)&Ps[c0 * 64 + ((mf * 16 + g * 4) ^ s8)] = pv;
    }
    psum += __shfl_xor(psum, 16);
    psum += __shfl_xor(psum, 32);
    lrun = lrun * alpha + psum;
    mrun = mnew;
#pragma unroll
    for (int mf = 0; mf < 4; ++mf) o[mf] *= alpha;

    // O^T += Vt @ P^T : 4 d-frags x 2 k-steps, V direct from global
    __builtin_amdgcn_s_setprio(1);
#pragma unroll
    for (int kk = 0; kk < 2; ++kk) {
      sx8 pbf = *(const sx8*)&Ps[c0 * 64 + ((kk * 32 + g * 8) ^ s8)];
#pragma unroll
      for (int mf = 0; mf < 4; ++mf) {
        sx8 vaf = *(const sx8*)&Vp[(size_t)(mf * 16 + c0) * 1024 + kv0 + kk * 32 + g * 8];
        o[mf] = mfma16(vaf, pbf, o[mf]);
      }
    }
    __builtin_amdgcn_s_setprio(0);
  }

  // store O^T -> attn_out[b][s=q][h*64+d] (merge heads), bf16
  float inv = 1.0f / lrun;
  int q = q0 + c0;
#pragma unroll
  for (int mf = 0; mf < 4; ++mf) {
    sx4 v;
#pragma unroll
    for (int r = 0; r < 4; ++r) v[r] = f2bf(o[mf][r] * inv);
    int d0 = mf * 16 + g * 4;
    *(sx4*)&AO[((size_t)(b * 1024 + q)) * 1024 + h * 64 + d0] = v;
  }
}

// ---------------- launch ----------------------------------------------------
extern "C" void kernel_launch(void* const* d_in, const int* in_sizes, int n_in,
                              void* d_out, int out_size, void* d_ws, size_t ws_size,
                              hipStream_t stream) {
  const float* hs  = (const float*)d_in[0];
  const float* caw = (const float*)d_in[1];
  const float* cab = (const float*)d_in[2];
  const float* cpw = (const float*)d_in[3];
  const float* cpb = (const float*)d_in[4];
  const float* afw = (const float*)d_in[5];
  const float* afb = (const float*)d_in[6];
  float* out = (float*)d_out;
  char* ws = (char*)d_ws;

  // workspace layout (40 MB): hsb/ao overlap at [0,8MB)
  short* hsb    = (short*)(ws);                    // [4096][1024] bf16 (dead after gemm1)
  short* ao     = (short*)(ws);                    // [4096][1024] bf16 (attn out)
  short* wqkvt  = (short*)(ws + ((size_t)8  << 20));  // [3072][1024] bf16
  short* wprojt = (short*)(ws + ((size_t)14 << 20));  // [1024][1024] bf16
  short* Qg     = (short*)(ws + ((size_t)16 << 20));  // [4][16][1024][64]
  short* Kg     = (short*)(ws + ((size_t)24 << 20));  // [4][16][1024][64]
  short* Vtg    = (short*)(ws + ((size_t)32 << 20));  // [4][16][64][1024]

  cast_bf16<<<4096, 256, 0, stream>>>(hs, hsb, 1048576);
  transpose_bf16<<<dim3(96, 32), 256, 0, stream>>>(caw, wqkvt, 1024, 3072);
  transpose_bf16<<<dim3(32, 32), 256, 0, stream>>>(cpw, wprojt, 1024, 1024);
  gemm_bt<0><<<dim3(24, 32), 256, 0, stream>>>(hsb, wqkvt, cab, nullptr, nullptr,
                                               Qg, Kg, Vtg, nullptr, 4096, 3072, 1024);
  attn_kernel<<<4096, 64, 0, stream>>>(Qg, Kg, Vtg, ao);
  gemm_bt<1><<<dim3(8, 32), 256, 0, stream>>>(ao, wprojt, cpb, afw, afb,
                                              nullptr, nullptr, nullptr, out, 4096, 1024, 1024);
}

// Round 6
// 140.013 us; speedup vs baseline: 1.0067x; 1.0067x over previous
//
#include <hip/hip_runtime.h>

// AffineGPT2Attention: B=4, S=1024, D=1024, H=16, Dh=64
// Pipeline: cast hs->bf16; transpose+cast weights; QKV GEMM (bf16 MFMA, scatter
// epilogue to Q[b][h][s][d] (pre-scaled by 0.125*log2e), K[b][h][s][d],
// Vt[b][h][d][s]); flash attention (1-wave blocks, 16q/wave, batched-MLP
// direct-global K/V frags); proj GEMM with bias+affine -> f32 out.

typedef __attribute__((ext_vector_type(4))) float  fx4;
typedef __attribute__((ext_vector_type(4))) short  sx4;
typedef __attribute__((ext_vector_type(8))) short  sx8;
typedef __attribute__((ext_vector_type(4))) float  f32x4;
typedef __attribute__((ext_vector_type(8))) __bf16 bf16x8;

#define DEVI static __device__ __forceinline__

DEVI short f2bf(float f) {  // f32 -> bf16 (RNE)
  unsigned u = __builtin_bit_cast(unsigned, f);
  u = (u + 0x7FFFu + ((u >> 16) & 1u)) >> 16;
  return (short)u;
}

DEVI fx4 mfma16(sx8 a, sx8 b, fx4 c) {
  return __builtin_amdgcn_mfma_f32_16x16x32_bf16(
      __builtin_bit_cast(bf16x8, a), __builtin_bit_cast(bf16x8, b), c, 0, 0, 0);
}

DEVI void gl_lds16(const void* g, void* l) {  // async global->LDS, 16B/lane
  __builtin_amdgcn_global_load_lds(
      (const __attribute__((address_space(1))) void*)g,
      (__attribute__((address_space(3))) void*)l, 16, 0, 0);
}

// ---------------- elementwise f32 -> bf16 cast (vectorized) ----------------
__global__ __launch_bounds__(256) void cast_bf16(const float* __restrict__ in,
                                                 short* __restrict__ out, int n4) {
  int i = blockIdx.x * blockDim.x + threadIdx.x;
  if (i < n4) {
    f32x4 v = *(const f32x4*)&in[(size_t)i * 4];
    sx4 o;
#pragma unroll
    for (int j = 0; j < 4; ++j) o[j] = f2bf(v[j]);
    *(sx4*)&out[(size_t)i * 4] = o;
  }
}

// ---------------- transpose + cast: in[R][C] f32 -> out[C][R] bf16 ----------
__global__ __launch_bounds__(256) void transpose_bf16(const float* __restrict__ in,
                                                      short* __restrict__ out,
                                                      int R, int C) {
  __shared__ float t[32][33];
  int tx = threadIdx.x & 31, ty = threadIdx.x >> 5;
  int r0 = blockIdx.y * 32, c0 = blockIdx.x * 32;
#pragma unroll
  for (int i = 0; i < 4; ++i)
    t[ty + i * 8][tx] = in[(size_t)(r0 + ty + i * 8) * C + c0 + tx];
  __syncthreads();
#pragma unroll
  for (int i = 0; i < 4; ++i)
    out[(size_t)(c0 + ty + i * 8) * R + r0 + tx] = f2bf(t[tx][ty + i * 8]);
}

// ---------------- GEMM: C[M][N] = A[M][K] @ Bt[N][K]^T ----------------------
// BM=BN=128, BK=64, 4 waves (2x2), each wave 64x64 = 4x4 frags of 16x16x32.
// EPI 0: qkv scatter epilogue (+bias, Q pre-scaled). EPI 1: proj (+bias,affine).
template <int EPI>
__global__ __launch_bounds__(256) void gemm_bt(
    const short* __restrict__ A, const short* __restrict__ Bt,
    const float* __restrict__ bias, const float* __restrict__ aw,
    const float* __restrict__ ab, short* __restrict__ Qg, short* __restrict__ Kg,
    short* __restrict__ Vtg, float* __restrict__ Out, int M, int N, int K) {
  __shared__ __align__(16) short As[128][64];
  __shared__ __align__(16) short Bs[128][64];
  const int tid = threadIdx.x, lane = tid & 63, w = tid >> 6;
  const int bn = blockIdx.x, bm = blockIdx.y;
  const int wm = w >> 1, wn = w & 1;
  const int c0 = lane & 15, g = lane >> 4;
  const int lr8 = lane >> 3;              // row within 8-row staging chunk
  const int ls8 = (lane & 7) ^ lr8;       // inverse-swizzled source slot
  fx4 acc[4][4] = {};

  for (int kt = 0; kt < K; kt += 64) {
#pragma unroll
    for (int i = 0; i < 4; ++i) {
      int r = w * 32 + i * 8;
      gl_lds16(&A[(size_t)(bm * 128 + r + lr8) * K + kt + ls8 * 8], &As[r][0]);
      gl_lds16(&Bt[(size_t)(bn * 128 + r + lr8) * K + kt + ls8 * 8], &Bs[r][0]);
    }
    __syncthreads();
#pragma unroll
    for (int kk = 0; kk < 2; ++kk) {
      sx8 af[4], bf[4];
      int sb = kk * 4 + g;
#pragma unroll
      for (int m = 0; m < 4; ++m) {
        int row = wm * 64 + m * 16 + c0;
        af[m] = *(const sx8*)&As[row][(sb ^ (row & 7)) * 8];
      }
#pragma unroll
      for (int n = 0; n < 4; ++n) {
        int row = wn * 64 + n * 16 + c0;
        bf[n] = *(const sx8*)&Bs[row][(sb ^ (row & 7)) * 8];
      }
#pragma unroll
      for (int m = 0; m < 4; ++m)
#pragma unroll
        for (int n = 0; n < 4; ++n) acc[m][n] = mfma16(af[m], bf[n], acc[m][n]);
    }
    __syncthreads();
  }

  // epilogue: C/D layout: row = (lane>>4)*4 + r, col = lane&15 (within frag)
  const float SCALE_Q = 0.125f * 1.4426950408889634f;  // fold 1/sqrt(64)*log2e
#pragma unroll
  for (int m = 0; m < 4; ++m) {
#pragma unroll
    for (int n = 0; n < 4; ++n) {
      int col = bn * 128 + wn * 64 + n * 16 + c0;
      int row0 = bm * 128 + wm * 64 + m * 16 + g * 4;
      if (EPI == 0) {
        float bv = bias[col];
        int b = row0 >> 10, s0 = row0 & 1023;
        if (col < 1024) {
          int h = col >> 6, d = col & 63;
          size_t base = ((size_t)(b * 16 + h) * 1024) * 64 + d;
#pragma unroll
          for (int r = 0; r < 4; ++r)
            Qg[base + (size_t)(s0 + r) * 64] = f2bf((acc[m][n][r] + bv) * SCALE_Q);
        } else if (col < 2048) {
          int c = col - 1024, h = c >> 6, d = c & 63;
          size_t base = ((size_t)(b * 16 + h) * 1024) * 64 + d;
#pragma unroll
          for (int r = 0; r < 4; ++r)
            Kg[base + (size_t)(s0 + r) * 64] = f2bf(acc[m][n][r] + bv);
        } else {
          int c = col - 2048, h = c >> 6, d = c & 63;
          sx4 v;
#pragma unroll
          for (int r = 0; r < 4; ++r) v[r] = f2bf(acc[m][n][r] + bv);
          *(sx4*)&Vtg[((size_t)(b * 16 + h) * 64 + d) * 1024 + s0] = v;
        }
      } else {
        float bv = bias[col], wv = aw[col], av = ab[col];
#pragma unroll
        for (int r = 0; r < 4; ++r)
          Out[(size_t)(row0 + r) * N + col] = (acc[m][n][r] + bv) * wv + av;
      }
    }
  }
}

// ---------------- flash attention (causal), 1-wave blocks -------------------
// Grid 4096: bid -> j = 63 - (bid>>6) (16-row q-slice, long waves first),
// bh = bid & 63. Each block = ONE wave, 16 q rows, KVBLK=64.
// All 16 K/V fragment loads for a tile are BATCH-ISSUED into registers and
// pinned with sched_barrier(0) before any MFMA -> 1 latency per tile, not 16
// (round-5 at VGPR=44 serialized every load: 10.5K cy/tile).
// Scores pre-scaled (Q folded with 0.125*log2e) -> p = exp2(z - m).
// S^T = K @ Q^T  (C/D: row=kv, col=q -> q lane-local => cheap softmax)
// O^T = Vt @ P^T (C/D: row=d,  col=q). Last kv-tile always masked.
__global__ __launch_bounds__(64, 3) void attn_kernel(const short* __restrict__ Qg,
                                                     const short* __restrict__ Kg,
                                                     const short* __restrict__ Vtg,
                                                     short* __restrict__ AO) {
  __shared__ __align__(16) short Ps[16 * 64];  // 2 KB
  const int lane = threadIdx.x & 63;
  const int bid = blockIdx.x;
  const int j = 63 - (bid >> 6), bh = bid & 63;
  const int b = bh >> 4, h = bh & 15;
  const int c0 = lane & 15, g = lane >> 4;
  const int q0 = j << 4;
  const short* Qp = Qg + (size_t)bh * 65536;
  const short* Kp = Kg + (size_t)bh * 65536;
  const short* Vp = Vtg + (size_t)bh * 65536;
  const int s8 = (c0 & 7) * 8;  // P swizzle

  sx8 qf[2];  // B-frags of Q: col=q (lane&15), k=d ((lane>>4)*8+jj)
#pragma unroll
  for (int kk = 0; kk < 2; ++kk)
    qf[kk] = *(const sx8*)&Qp[(size_t)(q0 + c0) * 64 + kk * 32 + g * 8];

  fx4 o[4] = {};
  float mrun = -1e30f, lrun = 0.f;
  const int ntiles = (q0 + 79) >> 6;  // causal: kv <= q0+15
  const int q_glob = q0 + c0;

  for (int kvt = 0; kvt < ntiles; ++kvt) {
    const int kv0 = kvt * 64;

    // batch-issue ALL K and V fragment loads for this tile (16x dwordx4)
    sx8 k0[4], k1[4], v0[4], v1[4];
#pragma unroll
    for (int mf = 0; mf < 4; ++mf) {
      const short* kr = &Kp[(size_t)(kv0 + mf * 16 + c0) * 64 + g * 8];
      k0[mf] = *(const sx8*)kr;
      k1[mf] = *(const sx8*)(kr + 32);
    }
#pragma unroll
    for (int mf = 0; mf < 4; ++mf) {
      const short* vr = &Vp[(size_t)(mf * 16 + c0) * 1024 + kv0 + g * 8];
      v0[mf] = *(const sx8*)vr;
      v1[mf] = *(const sx8*)(vr + 32);
    }
    __builtin_amdgcn_sched_barrier(0);  // do NOT sink these loads

    // S^T = K @ Q^T : 4 kv-frags
    fx4 st[4];
    __builtin_amdgcn_s_setprio(1);
#pragma unroll
    for (int mf = 0; mf < 4; ++mf) {
      fx4 z = {0.f, 0.f, 0.f, 0.f};
      z = mfma16(k0[mf], qf[0], z);
      st[mf] = mfma16(k1[mf], qf[1], z);
    }
    __builtin_amdgcn_s_setprio(0);

    // online softmax (fixed q per lane)
    float pmax = -1e30f;
    if (kvt == ntiles - 1) {  // diagonal tile: apply causal mask
#pragma unroll
      for (int mf = 0; mf < 4; ++mf)
#pragma unroll
        for (int r = 0; r < 4; ++r) {
          int kv = kv0 + mf * 16 + g * 4 + r;
          float z = (kv > q_glob) ? -1e30f : st[mf][r];
          st[mf][r] = z;
          pmax = fmaxf(pmax, z);
        }
    } else {
#pragma unroll
      for (int mf = 0; mf < 4; ++mf)
#pragma unroll
        for (int r = 0; r < 4; ++r) pmax = fmaxf(pmax, st[mf][r]);
    }
    pmax = fmaxf(pmax, __shfl_xor(pmax, 16));
    pmax = fmaxf(pmax, __shfl_xor(pmax, 32));
    float mnew = fmaxf(mrun, pmax);
    float alpha = __builtin_amdgcn_exp2f(mrun - mnew);
    float psum = 0.f;
#pragma unroll
    for (int mf = 0; mf < 4; ++mf) {
      sx4 pv;
#pragma unroll
      for (int r = 0; r < 4; ++r) {
        float pp = __builtin_amdgcn_exp2f(st[mf][r] - mnew);
        psum += pp;
        pv[r] = f2bf(pp);
      }
      *(sx4*)&Ps[c0 * 64 + ((mf * 16 + g * 4) ^ s8)] = pv;
    }
    psum += __shfl_xor(psum, 16);
    psum += __shfl_xor(psum, 32);
    lrun = lrun * alpha + psum;
    mrun = mnew;
#pragma unroll
    for (int mf = 0; mf < 4; ++mf) o[mf] *= alpha;

    // O^T += Vt @ P^T : 4 d-frags x 2 k-steps (V already in registers)
    __builtin_amdgcn_s_setprio(1);
#pragma unroll
    for (int kk = 0; kk < 2; ++kk) {
      sx8 pbf = *(const sx8*)&Ps[c0 * 64 + ((kk * 32 + g * 8) ^ s8)];
#pragma unroll
      for (int mf = 0; mf < 4; ++mf)
        o[mf] = mfma16(kk ? v1[mf] : v0[mf], pbf, o[mf]);
    }
    __builtin_amdgcn_s_setprio(0);
  }

  // store O^T -> attn_out[b][s=q][h*64+d] (merge heads), bf16
  float inv = 1.0f / lrun;
  int q = q0 + c0;
#pragma unroll
  for (int mf = 0; mf < 4; ++mf) {
    sx4 v;
#pragma unroll
    for (int r = 0; r < 4; ++r) v[r] = f2bf(o[mf][r] * inv);
    int d0 = mf * 16 + g * 4;
    *(sx4*)&AO[((size_t)(b * 1024 + q)) * 1024 + h * 64 + d0] = v;
  }
}

// ---------------- launch ----------------------------------------------------
extern "C" void kernel_launch(void* const* d_in, const int* in_sizes, int n_in,
                              void* d_out, int out_size, void* d_ws, size_t ws_size,
                              hipStream_t stream) {
  const float* hs  = (const float*)d_in[0];
  const float* caw = (const float*)d_in[1];
  const float* cab = (const float*)d_in[2];
  const float* cpw = (const float*)d_in[3];
  const float* cpb = (const float*)d_in[4];
  const float* afw = (const float*)d_in[5];
  const float* afb = (const float*)d_in[6];
  float* out = (float*)d_out;
  char* ws = (char*)d_ws;

  // workspace layout (40 MB): hsb/ao overlap at [0,8MB)
  short* hsb    = (short*)(ws);                    // [4096][1024] bf16 (dead after gemm1)
  short* ao     = (short*)(ws);                    // [4096][1024] bf16 (attn out)
  short* wqkvt  = (short*)(ws + ((size_t)8  << 20));  // [3072][1024] bf16
  short* wprojt = (short*)(ws + ((size_t)14 << 20));  // [1024][1024] bf16
  short* Qg     = (short*)(ws + ((size_t)16 << 20));  // [4][16][1024][64]
  short* Kg     = (short*)(ws + ((size_t)24 << 20));  // [4][16][1024][64]
  short* Vtg    = (short*)(ws + ((size_t)32 << 20));  // [4][16][64][1024]

  cast_bf16<<<4096, 256, 0, stream>>>(hs, hsb, 1048576);
  transpose_bf16<<<dim3(96, 32), 256, 0, stream>>>(caw, wqkvt, 1024, 3072);
  transpose_bf16<<<dim3(32, 32), 256, 0, stream>>>(cpw, wprojt, 1024, 1024);
  gemm_bt<0><<<dim3(24, 32), 256, 0, stream>>>(hsb, wqkvt, cab, nullptr, nullptr,
                                               Qg, Kg, Vtg, nullptr, 4096, 3072, 1024);
  attn_kernel<<<4096, 64, 0, stream>>>(Qg, Kg, Vtg, ao);
  gemm_bt<1><<<dim3(8, 32), 256, 0, stream>>>(ao, wprojt, cpb, afw, afb,
                                              nullptr, nullptr, nullptr, out, 4096, 1024, 1024);
}

// Round 7
// 100.757 us; speedup vs baseline: 1.3990x; 1.3896x over previous
//
#include <hip/hip_runtime.h>

// AffineGPT2Attention: B=4, S=1024, D=1024, H=16, Dh=64
// Pipeline: cast hs->bf16; transpose+cast weights; QKV GEMM (bf16 MFMA, scatter
// epilogue to Q[b][h][s][d] (pre-scaled by 0.125*log2e), K[b][h][s][d],
// Vt[b][h][d][s]); flash attention (4-wave blocks, shared dbuf LDS K/V staged
// via global_load_lds + counted vmcnt + raw s_barrier); proj GEMM -> f32 out.

typedef __attribute__((ext_vector_type(4))) float  fx4;
typedef __attribute__((ext_vector_type(4))) short  sx4;
typedef __attribute__((ext_vector_type(8))) short  sx8;
typedef __attribute__((ext_vector_type(4))) float  f32x4;
typedef __attribute__((ext_vector_type(8))) __bf16 bf16x8;

#define DEVI static __device__ __forceinline__

DEVI short f2bf(float f) {  // f32 -> bf16 (RNE)
  unsigned u = __builtin_bit_cast(unsigned, f);
  u = (u + 0x7FFFu + ((u >> 16) & 1u)) >> 16;
  return (short)u;
}

DEVI fx4 mfma16(sx8 a, sx8 b, fx4 c) {
  return __builtin_amdgcn_mfma_f32_16x16x32_bf16(
      __builtin_bit_cast(bf16x8, a), __builtin_bit_cast(bf16x8, b), c, 0, 0, 0);
}

DEVI void gl_lds16(const void* g, void* l) {  // async global->LDS, 16B/lane
  __builtin_amdgcn_global_load_lds(
      (const __attribute__((address_space(1))) void*)g,
      (__attribute__((address_space(3))) void*)l, 16, 0, 0);
}

// ---------------- elementwise f32 -> bf16 cast (vectorized) ----------------
__global__ __launch_bounds__(256) void cast_bf16(const float* __restrict__ in,
                                                 short* __restrict__ out, int n4) {
  int i = blockIdx.x * blockDim.x + threadIdx.x;
  if (i < n4) {
    f32x4 v = *(const f32x4*)&in[(size_t)i * 4];
    sx4 o;
#pragma unroll
    for (int j = 0; j < 4; ++j) o[j] = f2bf(v[j]);
    *(sx4*)&out[(size_t)i * 4] = o;
  }
}

// ---------------- transpose + cast: in[R][C] f32 -> out[C][R] bf16 ----------
__global__ __launch_bounds__(256) void transpose_bf16(const float* __restrict__ in,
                                                      short* __restrict__ out,
                                                      int R, int C) {
  __shared__ float t[32][33];
  int tx = threadIdx.x & 31, ty = threadIdx.x >> 5;
  int r0 = blockIdx.y * 32, c0 = blockIdx.x * 32;
#pragma unroll
  for (int i = 0; i < 4; ++i)
    t[ty + i * 8][tx] = in[(size_t)(r0 + ty + i * 8) * C + c0 + tx];
  __syncthreads();
#pragma unroll
  for (int i = 0; i < 4; ++i)
    out[(size_t)(c0 + ty + i * 8) * R + r0 + tx] = f2bf(t[tx][ty + i * 8]);
}

// ---------------- GEMM: C[M][N] = A[M][K] @ Bt[N][K]^T ----------------------
// BM=BN=128, BK=64, 4 waves (2x2), each wave 64x64 = 4x4 frags of 16x16x32.
// EPI 0: qkv scatter epilogue (+bias, Q pre-scaled). EPI 1: proj (+bias,affine).
template <int EPI>
__global__ __launch_bounds__(256) void gemm_bt(
    const short* __restrict__ A, const short* __restrict__ Bt,
    const float* __restrict__ bias, const float* __restrict__ aw,
    const float* __restrict__ ab, short* __restrict__ Qg, short* __restrict__ Kg,
    short* __restrict__ Vtg, float* __restrict__ Out, int M, int N, int K) {
  __shared__ __align__(16) short As[128][64];
  __shared__ __align__(16) short Bs[128][64];
  const int tid = threadIdx.x, lane = tid & 63, w = tid >> 6;
  const int bn = blockIdx.x, bm = blockIdx.y;
  const int wm = w >> 1, wn = w & 1;
  const int c0 = lane & 15, g = lane >> 4;
  const int lr8 = lane >> 3;              // row within 8-row staging chunk
  const int ls8 = (lane & 7) ^ lr8;       // inverse-swizzled source slot
  fx4 acc[4][4] = {};

  for (int kt = 0; kt < K; kt += 64) {
#pragma unroll
    for (int i = 0; i < 4; ++i) {
      int r = w * 32 + i * 8;
      gl_lds16(&A[(size_t)(bm * 128 + r + lr8) * K + kt + ls8 * 8], &As[r][0]);
      gl_lds16(&Bt[(size_t)(bn * 128 + r + lr8) * K + kt + ls8 * 8], &Bs[r][0]);
    }
    __syncthreads();
#pragma unroll
    for (int kk = 0; kk < 2; ++kk) {
      sx8 af[4], bf[4];
      int sb = kk * 4 + g;
#pragma unroll
      for (int m = 0; m < 4; ++m) {
        int row = wm * 64 + m * 16 + c0;
        af[m] = *(const sx8*)&As[row][(sb ^ (row & 7)) * 8];
      }
#pragma unroll
      for (int n = 0; n < 4; ++n) {
        int row = wn * 64 + n * 16 + c0;
        bf[n] = *(const sx8*)&Bs[row][(sb ^ (row & 7)) * 8];
      }
#pragma unroll
      for (int m = 0; m < 4; ++m)
#pragma unroll
        for (int n = 0; n < 4; ++n) acc[m][n] = mfma16(af[m], bf[n], acc[m][n]);
    }
    __syncthreads();
  }

  // epilogue: C/D layout: row = (lane>>4)*4 + r, col = lane&15 (within frag)
  const float SCALE_Q = 0.125f * 1.4426950408889634f;  // fold 1/sqrt(64)*log2e
#pragma unroll
  for (int m = 0; m < 4; ++m) {
#pragma unroll
    for (int n = 0; n < 4; ++n) {
      int col = bn * 128 + wn * 64 + n * 16 + c0;
      int row0 = bm * 128 + wm * 64 + m * 16 + g * 4;
      if (EPI == 0) {
        float bv = bias[col];
        int b = row0 >> 10, s0 = row0 & 1023;
        if (col < 1024) {
          int h = col >> 6, d = col & 63;
          size_t base = ((size_t)(b * 16 + h) * 1024) * 64 + d;
#pragma unroll
          for (int r = 0; r < 4; ++r)
            Qg[base + (size_t)(s0 + r) * 64] = f2bf((acc[m][n][r] + bv) * SCALE_Q);
        } else if (col < 2048) {
          int c = col - 1024, h = c >> 6, d = c & 63;
          size_t base = ((size_t)(b * 16 + h) * 1024) * 64 + d;
#pragma unroll
          for (int r = 0; r < 4; ++r)
            Kg[base + (size_t)(s0 + r) * 64] = f2bf(acc[m][n][r] + bv);
        } else {
          int c = col - 2048, h = c >> 6, d = c & 63;
          sx4 v;
#pragma unroll
          for (int r = 0; r < 4; ++r) v[r] = f2bf(acc[m][n][r] + bv);
          *(sx4*)&Vtg[((size_t)(b * 16 + h) * 64 + d) * 1024 + s0] = v;
        }
      } else {
        float bv = bias[col], wv = aw[col], av = ab[col];
#pragma unroll
        for (int r = 0; r < 4; ++r)
          Out[(size_t)(row0 + r) * N + col] = (acc[m][n][r] + bv) * wv + av;
      }
    }
  }
}

// ---------------- flash attention (causal), LDS-staged K/V ------------------
// 1024 blocks, 4 waves each. Block owns 64 contiguous q rows (qt tile); wave w
// owns q rows [qt*64+16w, +16). All waves share K/V staged via global_load_lds
// into double-buffered LDS (zero VGPR cost for in-flight data). Per kv-tile:
//   STAGE(t+1) -> s_waitcnt vmcnt(4) -> s_barrier -> COMPUTE(t) -> s_barrier.
// Counted vmcnt keeps next-tile DMA in flight across the barrier (T3/T4);
// raw s_barrier (NOT __syncthreads: that drains vmcnt(0) and serializes DMA).
// 2nd barrier makes the 2-buffer rotation race-free. LDS 40KB -> 4 blocks/CU.
// bid map: qt of a CU's 4 sequential blocks (stride 256) sums to const -> tail
// balance. Scores pre-scaled (Q folded 0.125*log2e) -> p = exp2(z-m).
__global__ __launch_bounds__(256, 4) void attn_kernel(const short* __restrict__ Qg,
                                                      const short* __restrict__ Kg,
                                                      const short* __restrict__ Vtg,
                                                      short* __restrict__ AO) {
  __shared__ __align__(16) short Ks[2][64][64];   // 16 KB
  __shared__ __align__(16) short Vts[2][64][64];  // 16 KB
  __shared__ __align__(16) short Ps[4][16 * 64];  // 8 KB
  const int tid = threadIdx.x, lane = tid & 63, w = tid >> 6;
  const int bid = blockIdx.x;
  // bid = u*256 + bh*4 + j ; qt(u,j): u0->j, u1->7-j, u2->8+j, u3->15-j
  const int u = bid >> 8, v = bid & 255, bh = v >> 2, jj = v & 3;
  const int qt = (u == 0) ? jj : (u == 1) ? 7 - jj : (u == 2) ? 8 + jj : 15 - jj;
  const int b = bh >> 4, h = bh & 15;
  const int c0 = lane & 15, g = lane >> 4;
  const int lr8 = lane >> 3, ls8 = (lane & 7) ^ lr8;
  const int q0 = qt * 64 + w * 16;
  const short* Qp = Qg + (size_t)bh * 65536;
  const short* Kp = Kg + (size_t)bh * 65536;
  const short* Vp = Vtg + (size_t)bh * 65536;
  short* pbase = &Ps[w][0];
  const int s8 = (c0 & 7) * 8;  // P swizzle

  sx8 qf[2];  // B-frags of Q: col=q (lane&15), k=d ((lane>>4)*8+e)
#pragma unroll
  for (int kk = 0; kk < 2; ++kk)
    qf[kk] = *(const sx8*)&Qp[(size_t)(q0 + c0) * 64 + kk * 32 + g * 8];

  fx4 o[4] = {};
  float mrun = -1e30f, lrun = 0.f;
  const int q_glob = q0 + c0;

  // stage K/V tile kv0 into buffer bf: 4 gl_lds per wave (2 K + 2 V)
  auto STAGE = [&](int bf, int kv0) {
#pragma unroll
    for (int i = 0; i < 2; ++i) {
      int idx = w * 2 + i;  // 8-row chunk
      gl_lds16(&Kp[(size_t)(kv0 + idx * 8 + lr8) * 64 + ls8 * 8], &Ks[bf][idx * 8][0]);
    }
#pragma unroll
    for (int i = 0; i < 2; ++i) {
      int idx = w * 2 + i;
      gl_lds16(&Vp[(size_t)(idx * 8 + lr8) * 1024 + kv0 + ls8 * 8], &Vts[bf][idx * 8][0]);
    }
  };

  STAGE(0, 0);
  for (int t = 0; t <= qt; ++t) {
    const int kv0 = t * 64;
    const int bf = t & 1;
    const bool more = t < qt;
    if (more) {
      STAGE(bf ^ 1, kv0 + 64);
      asm volatile("s_waitcnt vmcnt(4)" ::: "memory");
    } else {
      asm volatile("s_waitcnt vmcnt(0)" ::: "memory");
    }
    __builtin_amdgcn_s_barrier();  // raw: does NOT drain the 4 in-flight loads

    // S^T = K @ Q^T : 4 kv-frags from LDS
    fx4 st[4];
    __builtin_amdgcn_s_setprio(1);
#pragma unroll
    for (int mf = 0; mf < 4; ++mf) {
      int row = mf * 16 + c0;
      sx8 kf0 = *(const sx8*)&Ks[bf][row][(g ^ (row & 7)) * 8];
      sx8 kf1 = *(const sx8*)&Ks[bf][row][((4 + g) ^ (row & 7)) * 8];
      fx4 z = {0.f, 0.f, 0.f, 0.f};
      z = mfma16(kf0, qf[0], z);
      st[mf] = mfma16(kf1, qf[1], z);
    }
    __builtin_amdgcn_s_setprio(0);

    // online softmax (fixed q per lane)
    float pmax = -1e30f;
    if (t == qt) {  // diagonal tile: causal mask
#pragma unroll
      for (int mf = 0; mf < 4; ++mf)
#pragma unroll
        for (int r = 0; r < 4; ++r) {
          int kv = kv0 + mf * 16 + g * 4 + r;
          float z = (kv > q_glob) ? -1e30f : st[mf][r];
          st[mf][r] = z;
          pmax = fmaxf(pmax, z);
        }
    } else {
#pragma unroll
      for (int mf = 0; mf < 4; ++mf)
#pragma unroll
        for (int r = 0; r < 4; ++r) pmax = fmaxf(pmax, st[mf][r]);
    }
    pmax = fmaxf(pmax, __shfl_xor(pmax, 16));
    pmax = fmaxf(pmax, __shfl_xor(pmax, 32));
    float mnew = fmaxf(mrun, pmax);
    float alpha = __builtin_amdgcn_exp2f(mrun - mnew);
    float psum = 0.f;
#pragma unroll
    for (int mf = 0; mf < 4; ++mf) {
      sx4 pv;
#pragma unroll
      for (int r = 0; r < 4; ++r) {
        float pp = __builtin_amdgcn_exp2f(st[mf][r] - mnew);
        psum += pp;
        pv[r] = f2bf(pp);
      }
      *(sx4*)&pbase[c0 * 64 + ((mf * 16 + g * 4) ^ s8)] = pv;
    }
    psum += __shfl_xor(psum, 16);
    psum += __shfl_xor(psum, 32);
    lrun = lrun * alpha + psum;
    mrun = mnew;
#pragma unroll
    for (int mf = 0; mf < 4; ++mf) o[mf] *= alpha;

    // O^T += Vt @ P^T : 4 d-frags x 2 k-steps, V from LDS
    __builtin_amdgcn_s_setprio(1);
#pragma unroll
    for (int kk = 0; kk < 2; ++kk) {
      sx8 pbf = *(const sx8*)&pbase[c0 * 64 + ((kk * 32 + g * 8) ^ s8)];
#pragma unroll
      for (int mf = 0; mf < 4; ++mf) {
        int row = mf * 16 + c0;
        sx8 vaf = *(const sx8*)&Vts[bf][row][((kk * 4 + g) ^ (row & 7)) * 8];
        o[mf] = mfma16(vaf, pbf, o[mf]);
      }
    }
    __builtin_amdgcn_s_setprio(0);
    __builtin_amdgcn_s_barrier();  // buffer-rotation safety
  }

  // store O^T -> attn_out[b][s=q][h*64+d] (merge heads), bf16
  float inv = 1.0f / lrun;
  int q = q0 + c0;
#pragma unroll
  for (int mf = 0; mf < 4; ++mf) {
    sx4 v4;
#pragma unroll
    for (int r = 0; r < 4; ++r) v4[r] = f2bf(o[mf][r] * inv);
    int d0 = mf * 16 + g * 4;
    *(sx4*)&AO[((size_t)(b * 1024 + q)) * 1024 + h * 64 + d0] = v4;
  }
}

// ---------------- launch ----------------------------------------------------
extern "C" void kernel_launch(void* const* d_in, const int* in_sizes, int n_in,
                              void* d_out, int out_size, void* d_ws, size_t ws_size,
                              hipStream_t stream) {
  const float* hs  = (const float*)d_in[0];
  const float* caw = (const float*)d_in[1];
  const float* cab = (const float*)d_in[2];
  const float* cpw = (const float*)d_in[3];
  const float* cpb = (const float*)d_in[4];
  const float* afw = (const float*)d_in[5];
  const float* afb = (const float*)d_in[6];
  float* out = (float*)d_out;
  char* ws = (char*)d_ws;

  // workspace layout (40 MB): hsb/ao overlap at [0,8MB)
  short* hsb    = (short*)(ws);                    // [4096][1024] bf16 (dead after gemm1)
  short* ao     = (short*)(ws);                    // [4096][1024] bf16 (attn out)
  short* wqkvt  = (short*)(ws + ((size_t)8  << 20));  // [3072][1024] bf16
  short* wprojt = (short*)(ws + ((size_t)14 << 20));  // [1024][1024] bf16
  short* Qg     = (short*)(ws + ((size_t)16 << 20));  // [4][16][1024][64]
  short* Kg     = (short*)(ws + ((size_t)24 << 20));  // [4][16][1024][64]
  short* Vtg    = (short*)(ws + ((size_t)32 << 20));  // [4][16][64][1024]

  cast_bf16<<<4096, 256, 0, stream>>>(hs, hsb, 1048576);
  transpose_bf16<<<dim3(96, 32), 256, 0, stream>>>(caw, wqkvt, 1024, 3072);
  transpose_bf16<<<dim3(32, 32), 256, 0, stream>>>(cpw, wprojt, 1024, 1024);
  gemm_bt<0><<<dim3(24, 32), 256, 0, stream>>>(hsb, wqkvt, cab, nullptr, nullptr,
                                               Qg, Kg, Vtg, nullptr, 4096, 3072, 1024);
  attn_kernel<<<1024, 256, 0, stream>>>(Qg, Kg, Vtg, ao);
  gemm_bt<1><<<dim3(8, 32), 256, 0, stream>>>(ao, wprojt, cpb, afw, afb,
                                              nullptr, nullptr, nullptr, out, 4096, 1024, 1024);
}